// Round 2
// baseline (415.010 us; speedup 1.0000x reference)
//
#include <hip/hip_runtime.h>
#include <math.h>

// NetVLAD v7 — G1+G2 FUSED into one kernel (fused_vlad).
// Per block (b, 128-pixel slice): phase 1 computes logits+softmax (as G1),
// alpha kept in LDS as_[64][136] bf16 (k-major, padded) — never written to
// global. Phase 2 consumes it immediately: vlad[d,k] += sum_n x[d,n]*alpha[k,n]
// with x loaded global->register (L3-hot re-read, rows are wave-private so no
// LDS staging), hi/lo bf16 split, atomicAdd flush into pre-zeroed vlad.
// Deletes: alpha HBM round-trip (25.6 MB), G2's LDS staging + barriers, 1 launch.
// B=32, D=512, K=64, N=3136.

#define NN 3136
#define DD 512
#define KK 64
#define BB 32

typedef short bf16x8 __attribute__((ext_vector_type(8)));
typedef float f32x4  __attribute__((ext_vector_type(4)));

#define SEL_HI   0x05040100u   // (a_low16<<16) | b_low16
#define SEL_LO   0x07060302u   // (a_high16<<16) | b_high16
#define SEL_PACK 0x07060302u   // a=lo_f32, b=x_f32 -> (lo_hi16<<16) | x_hi16

union FragU { uint4 u; bf16x8 f; };

static __device__ inline bf16x8 frag4(unsigned a, unsigned b, unsigned c, unsigned d) {
    FragU x; x.u = make_uint4(a, b, c, d); return x.f;
}

static __device__ inline unsigned short bf16_rne(float f) {
    unsigned u = __float_as_uint(f);
    return (unsigned short)((u + 0x7FFFu + ((u >> 16) & 1u)) >> 16);
}

// ---------------------------------------------------------------- wprep
// grid 1024: W split (i<32768), zero vlad (1M floats), zero asum.
__global__ __launch_bounds__(256) void wprep_kernel(
    const float* __restrict__ w, unsigned short* __restrict__ wh,
    unsigned short* __restrict__ wl, float* __restrict__ asum,
    float* __restrict__ vlad)
{
    const int i = blockIdx.x * 256 + threadIdx.x;    // < 262144
    if (i < 32768) {
        float v = w[i];
        float hif = __uint_as_float(__float_as_uint(v) & 0xFFFF0000u);
        float lof = v - hif;
        wh[i] = (unsigned short)(__float_as_uint(v) >> 16);
        wl[i] = (unsigned short)(__float_as_uint(lof) >> 16);
    }
    *(float4*)&vlad[(size_t)i * 4] = make_float4(0.f, 0.f, 0.f, 0.f);
    if (i < 2048) asum[i] = 0.f;
}

// ---------------------------------------------------------------- fused G1+G2
// grid (25, 32), block 256 (4 waves).
// Phase 1: logits+softmax+asum for 128 pixels, alpha -> LDS (bf16, [k][n]).
// Phase 2: vlad[d,k] partial GEMM over this block's 128 pixels, atomics out.
__global__ __launch_bounds__(256) void fused_vlad(
    const float* __restrict__ x,          // [B,D,N] fp32
    const unsigned short* __restrict__ wh,// [64][512] hi
    const unsigned short* __restrict__ wl,// [64][512] lo
    const float* __restrict__ bias,       // [64]
    float* __restrict__ asum,             // [B,K] fp32 (pre-zeroed)
    float* __restrict__ vlad)             // [B,D,K] fp32 (pre-zeroed)
{
    const int b  = blockIdx.y;
    const int n0 = blockIdx.x * 128;
    const int t  = threadIdx.x;
    const int lane = t & 63;
    const int wv   = t >> 6;
    const int c = lane & 15;
    const int q = lane >> 4;

    __shared__ __align__(16) unsigned xs[128][36];        // [n][d] packed u32
    __shared__ __align__(16) unsigned short wsh[64][40];  // [k][d] hi
    __shared__ __align__(16) unsigned short wsl[64][40];  // [k][d] lo
    __shared__ __align__(16) unsigned short as_[64][136]; // alpha [k][n] bf16, padded

    f32x4 acc[4][2];
    #pragma unroll
    for (int mt = 0; mt < 4; mt++)
        #pragma unroll
        for (int r = 0; r < 4; r++) {
            float bv = bias[mt * 16 + q * 4 + r];
            acc[mt][0][r] = bv; acc[mt][1][r] = bv;
        }

    const float* xb = x + (size_t)b * DD * NN;
    const int n4 = t & 31;        // n offset within 32
    const int dr = t >> 5;        // 0..7 -> d col-group
    const int wrow = t >> 2, wc8 = t & 3;

    // ---- prefetch dc=0
    float xr[16];
    uint4 wrh, wrl;
    {
        #pragma unroll
        for (int j = 0; j < 4; j++) {
            int nn = n0 + n4 + 32 * j;
            if (nn > NN - 1) nn = NN - 1;
            #pragma unroll
            for (int p = 0; p < 4; p++)
                xr[j * 4 + p] = xb[(size_t)(dr * 4 + p) * NN + nn];
        }
        wrh = *(const uint4*)&wh[(size_t)wrow * DD + wc8 * 8];
        wrl = *(const uint4*)&wl[(size_t)wrow * DD + wc8 * 8];
    }

    for (int dc = 0; dc < 16; dc++) {
        // pack current regs (frees xr for the next prefetch)
        uint4 xp[4];
        #pragma unroll
        for (int j = 0; j < 4; j++) {
            unsigned pk[4];
            #pragma unroll
            for (int p = 0; p < 4; p++) {
                float v = xr[j * 4 + p];
                float hif = __uint_as_float(__float_as_uint(v) & 0xFFFF0000u);
                float lof = v - hif;
                pk[p] = __builtin_amdgcn_perm(__float_as_uint(lof), __float_as_uint(v), SEL_PACK);
            }
            xp[j] = make_uint4(pk[0], pk[1], pk[2], pk[3]);
        }
        uint4 wch = wrh, wcl = wrl;

        // prefetch dc+1 (in flight across the MFMA section below)
        if (dc < 15) {
            const int d0 = (dc + 1) * 32;
            #pragma unroll
            for (int j = 0; j < 4; j++) {
                int nn = n0 + n4 + 32 * j;
                if (nn > NN - 1) nn = NN - 1;
                #pragma unroll
                for (int p = 0; p < 4; p++)
                    xr[j * 4 + p] = xb[(size_t)(d0 + dr * 4 + p) * NN + nn];
            }
            wrh = *(const uint4*)&wh[(size_t)wrow * DD + d0 + wc8 * 8];
            wrl = *(const uint4*)&wl[(size_t)wrow * DD + d0 + wc8 * 8];
        }

        __syncthreads();   // prev LDS consumers done
        #pragma unroll
        for (int j = 0; j < 4; j++)
            *(uint4*)&xs[n4 + 32 * j][dr * 4] = xp[j];
        *(uint4*)&wsh[wrow][wc8 * 8] = wch;
        *(uint4*)&wsl[wrow][wc8 * 8] = wcl;
        __syncthreads();   // LDS visible

        // fragments: A direct b128 from planes; B via perm from packed xs
        bf16x8 ah[4], al[4], bh[2], bl[2];
        #pragma unroll
        for (int mt = 0; mt < 4; mt++) {
            ah[mt] = *(const bf16x8*)&wsh[mt * 16 + c][q * 8];
            al[mt] = *(const bf16x8*)&wsl[mt * 16 + c][q * 8];
        }
        #pragma unroll
        for (int nt = 0; nt < 2; nt++) {
            const int row = wv * 32 + nt * 16 + c;
            uint4 p0 = *(const uint4*)&xs[row][q * 8];
            uint4 p1 = *(const uint4*)&xs[row][q * 8 + 4];
            bh[nt] = frag4(__builtin_amdgcn_perm(p0.y, p0.x, SEL_HI),
                           __builtin_amdgcn_perm(p0.w, p0.z, SEL_HI),
                           __builtin_amdgcn_perm(p1.y, p1.x, SEL_HI),
                           __builtin_amdgcn_perm(p1.w, p1.z, SEL_HI));
            bl[nt] = frag4(__builtin_amdgcn_perm(p0.y, p0.x, SEL_LO),
                           __builtin_amdgcn_perm(p0.w, p0.z, SEL_LO),
                           __builtin_amdgcn_perm(p1.y, p1.x, SEL_LO),
                           __builtin_amdgcn_perm(p1.w, p1.z, SEL_LO));
        }
        #pragma unroll
        for (int mt = 0; mt < 4; mt++)
            #pragma unroll
            for (int nt = 0; nt < 2; nt++) {
                acc[mt][nt] = __builtin_amdgcn_mfma_f32_16x16x32_bf16(ah[mt], bh[nt], acc[mt][nt], 0, 0, 0);
                acc[mt][nt] = __builtin_amdgcn_mfma_f32_16x16x32_bf16(ah[mt], bl[nt], acc[mt][nt], 0, 0, 0);
                acc[mt][nt] = __builtin_amdgcn_mfma_f32_16x16x32_bf16(al[mt], bh[nt], acc[mt][nt], 0, 0, 0);
            }
    }

    // fused softmax over 64 clusters + bf16 -> LDS alpha + asum partials
    float sa[4][4];
    #pragma unroll
    for (int mt = 0; mt < 4; mt++)
        #pragma unroll
        for (int r = 0; r < 4; r++) sa[mt][r] = 0.f;

    #pragma unroll
    for (int nt = 0; nt < 2; nt++) {
        float mx = -1e30f;
        #pragma unroll
        for (int mt = 0; mt < 4; mt++)
            #pragma unroll
            for (int r = 0; r < 4; r++) mx = fmaxf(mx, acc[mt][nt][r]);
        mx = fmaxf(mx, __shfl_xor(mx, 16));
        mx = fmaxf(mx, __shfl_xor(mx, 32));
        float s = 0.f;
        #pragma unroll
        for (int mt = 0; mt < 4; mt++)
            #pragma unroll
            for (int r = 0; r < 4; r++) {
                float e = __expf(acc[mt][nt][r] - mx);
                acc[mt][nt][r] = e; s += e;
            }
        s += __shfl_xor(s, 16);
        s += __shfl_xor(s, 32);
        const float rinv = 1.0f / s;
        const int nloc = wv * 32 + nt * 16 + c;      // 0..127
        const bool ok = (n0 + nloc) < NN;
        #pragma unroll
        for (int mt = 0; mt < 4; mt++)
            #pragma unroll
            for (int r = 0; r < 4; r++) {
                unsigned short ub = bf16_rne(acc[mt][nt][r] * rinv);
                if (!ok) ub = 0;                      // invalid pixels contribute 0
                as_[mt * 16 + q * 4 + r][nloc] = ub;
                if (ok) sa[mt][r] += __uint_as_float((unsigned)ub << 16);  // dequantized
            }
    }
    #pragma unroll
    for (int off = 1; off <= 8; off <<= 1)
        #pragma unroll
        for (int mt = 0; mt < 4; mt++)
            #pragma unroll
            for (int r = 0; r < 4; r++)
                sa[mt][r] += __shfl_xor(sa[mt][r], off);
    if (c == 0) {
        #pragma unroll
        for (int mt = 0; mt < 4; mt++)
            #pragma unroll
            for (int r = 0; r < 4; r++)
                atomicAdd(&asum[b * KK + mt * 16 + q * 4 + r], sa[mt][r]);
    }

    __syncthreads();   // as_ visible to all waves

    // -------- phase 2: vlad[d,k] += sum_n x[d,n] * alpha[k,n] over 128 pixels
    // Wave wv owns d-rows [wv*128, wv*128+128). Two d-halves cap acc at 64 VGPR.
    // A-frag: x rows direct from global (L3-hot), hi/lo split.
    // B-frag: as_[k][n] ds_read_b128 (k=kt*16+c, n=ns*32+q*8 — 2-way-free banks).
    const float* xw = x + ((size_t)b * DD + wv * 128) * NN;
    float* pvb = vlad + ((size_t)b * DD + wv * 128) * KK;

    #pragma unroll
    for (int dh = 0; dh < 2; dh++) {
        f32x4 acc2[4][4];
        #pragma unroll
        for (int dt = 0; dt < 4; dt++)
            #pragma unroll
            for (int kt = 0; kt < 4; kt++)
                #pragma unroll
                for (int r = 0; r < 4; r++) acc2[dt][kt][r] = 0.f;

        #pragma unroll
        for (int ns = 0; ns < 4; ns++) {
            bf16x8 bfr[4];
            #pragma unroll
            for (int kt = 0; kt < 4; kt++)
                bfr[kt] = *(const bf16x8*)&as_[kt * 16 + c][ns * 32 + q * 8];
            int nn = n0 + ns * 32 + q * 8;           // multiple of 8
            if (nn > NN - 8) nn = NN - 8;            // clamp: alpha=0 there anyway
            #pragma unroll
            for (int dt = 0; dt < 4; dt++) {
                const size_t ro = (size_t)(dh * 64 + dt * 16 + c) * NN;
                const float4 va = *(const float4*)&xw[ro + nn];
                const float4 vb2 = *(const float4*)&xw[ro + nn + 4];
                unsigned ux = __float_as_uint(va.x),  uy = __float_as_uint(va.y);
                unsigned uz = __float_as_uint(va.z),  uw = __float_as_uint(va.w);
                unsigned vx = __float_as_uint(vb2.x), vy = __float_as_uint(vb2.y);
                unsigned vz = __float_as_uint(vb2.z), vw = __float_as_uint(vb2.w);
                bf16x8 ah = frag4(__builtin_amdgcn_perm(uy, ux, SEL_LO),
                                  __builtin_amdgcn_perm(uw, uz, SEL_LO),
                                  __builtin_amdgcn_perm(vy, vx, SEL_LO),
                                  __builtin_amdgcn_perm(vw, vz, SEL_LO));
                float lax = va.x - __uint_as_float(ux & 0xFFFF0000u);
                float lay = va.y - __uint_as_float(uy & 0xFFFF0000u);
                float laz = va.z - __uint_as_float(uz & 0xFFFF0000u);
                float law = va.w - __uint_as_float(uw & 0xFFFF0000u);
                float lbx = vb2.x - __uint_as_float(vx & 0xFFFF0000u);
                float lby = vb2.y - __uint_as_float(vy & 0xFFFF0000u);
                float lbz = vb2.z - __uint_as_float(vz & 0xFFFF0000u);
                float lbw = vb2.w - __uint_as_float(vw & 0xFFFF0000u);
                bf16x8 al2 = frag4(
                    __builtin_amdgcn_perm(__float_as_uint(lay), __float_as_uint(lax), SEL_LO),
                    __builtin_amdgcn_perm(__float_as_uint(law), __float_as_uint(laz), SEL_LO),
                    __builtin_amdgcn_perm(__float_as_uint(lby), __float_as_uint(lbx), SEL_LO),
                    __builtin_amdgcn_perm(__float_as_uint(lbw), __float_as_uint(lbz), SEL_LO));
                #pragma unroll
                for (int kt = 0; kt < 4; kt++) {
                    acc2[dt][kt] = __builtin_amdgcn_mfma_f32_16x16x32_bf16(ah,  bfr[kt], acc2[dt][kt], 0, 0, 0);
                    acc2[dt][kt] = __builtin_amdgcn_mfma_f32_16x16x32_bf16(al2, bfr[kt], acc2[dt][kt], 0, 0, 0);
                }
            }
        }
        #pragma unroll
        for (int dt = 0; dt < 4; dt++)
            #pragma unroll
            for (int r = 0; r < 4; r++) {
                const size_t dl = (size_t)(dh * 64 + dt * 16 + q * 4 + r) * KK;
                #pragma unroll
                for (int kt = 0; kt < 4; kt++)
                    atomicAdd(&pvb[dl + kt * 16 + c], acc2[dt][kt][r]);
            }
    }
}

// ---------------------------------------------------------------- combine
// grid (4, 32): vlad -= centers*asum (in place), psq partial sq-sums.
__global__ __launch_bounds__(256) void combine_norm(
    const float* __restrict__ centers, const float* __restrict__ asum,
    float* __restrict__ vlad, float* __restrict__ psq)
{
    const int dchunk = blockIdx.x;
    const int b = blockIdx.y;
    const int t = threadIdx.x;
    const int k4 = (t & 15) * 4;
    const int dq = t >> 4;          // 0..15
    const float4 av = *(const float4*)&asum[b * KK + k4];
    float sqx = 0.f, sqy = 0.f, sqz = 0.f, sqw = 0.f;
    for (int i = 0; i < 8; i++) {
        const int d = dchunk * 128 + i * 16 + dq;
        const size_t idx = ((size_t)b * DD + d) * KK + k4;
        float4 p = *(const float4*)&vlad[idx];
        const float4 cv = *(const float4*)&centers[d * KK + k4];
        float vx = p.x - cv.x * av.x, vy = p.y - cv.y * av.y;
        float vz = p.z - cv.z * av.z, vw = p.w - cv.w * av.w;
        *(float4*)&vlad[idx] = make_float4(vx, vy, vz, vw);
        sqx = fmaf(vx, vx, sqx); sqy = fmaf(vy, vy, sqy);
        sqz = fmaf(vz, vz, sqz); sqw = fmaf(vw, vw, sqw);
    }
    __shared__ float red[16][64];
    red[dq][k4 + 0] = sqx; red[dq][k4 + 1] = sqy;
    red[dq][k4 + 2] = sqz; red[dq][k4 + 3] = sqw;
    __syncthreads();
    if (t < 64) {
        float s = 0.f;
        #pragma unroll
        for (int qq = 0; qq < 16; qq++) s += red[qq][t];
        psq[(b * 4 + dchunk) * 64 + t] = s;
    }
}

// ---------------------------------------------------------------- finalize
__global__ __launch_bounds__(256) void finalize_kernel(
    const float* __restrict__ psq, const float* __restrict__ vlad,
    float* __restrict__ out)
{
    const int dchunk = blockIdx.x;
    const int b = blockIdx.y;
    const int t = threadIdx.x;
    __shared__ float cn[64];
    if (t < 64) {
        float s = psq[b * 256 + t] + psq[b * 256 + 64 + t]
                + psq[b * 256 + 128 + t] + psq[b * 256 + 192 + t];
        cn[t] = 1.0f / (sqrtf(s) * 8.0f);   // global norm of K unit cols == 8
    }
    __syncthreads();
    const int k4 = (t & 15) * 4;
    const int dq = t >> 4;
    const float4 cv = *(const float4*)&cn[k4];
    #pragma unroll
    for (int i = 0; i < 8; i++) {
        const size_t idx = ((size_t)b * DD + dchunk * 128 + i * 16 + dq) * KK + k4;
        float4 v = *(const float4*)&vlad[idx];
        *(float4*)&out[idx] = make_float4(v.x * cv.x, v.y * cv.y, v.z * cv.z, v.w * cv.w);
    }
}

// ---------------------------------------------------------------- launch
extern "C" void kernel_launch(void* const* d_in, const int* in_sizes, int n_in,
                              void* d_out, int out_size, void* d_ws, size_t ws_size,
                              hipStream_t stream) {
    const float* x       = (const float*)d_in[0];
    const float* conv_w  = (const float*)d_in[1];
    const float* conv_b  = (const float*)d_in[2];
    const float* centers = (const float*)d_in[3];
    float* out = (float*)d_out;

    unsigned short* wh = (unsigned short*)d_ws;     // 32768 ushort
    unsigned short* wl = wh + 32768;                // 32768 ushort
    float* asum = (float*)(wl + 32768);             // 2048
    float* vlad = asum + 2048;                      // 1,048,576
    float* psq  = vlad + 1048576;                   // 8192

    wprep_kernel   <<<dim3(1024),    dim3(256), 0, stream>>>(conv_w, wh, wl, asum, vlad);
    fused_vlad     <<<dim3(25, BB),  dim3(256), 0, stream>>>(x, wh, wl, conv_b, asum, vlad);
    combine_norm   <<<dim3(4, BB),   dim3(256), 0, stream>>>(centers, asum, vlad, psq);
    finalize_kernel<<<dim3(4, BB),   dim3(256), 0, stream>>>(psq, vlad, out);
}

// Round 3
// 408.135 us; speedup vs baseline: 1.0168x; 1.0168x over previous
//
#include <hip/hip_runtime.h>
#include <math.h>

// NetVLAD v8 — fused G1+G2 with the latency fix:
//  * as_ (alpha LDS) UNIONED into xs region (disjoint lifetimes) -> LDS 28.7 KB
//    -> 5 blocks/CU capacity (was 3 at 46 KB).
//  * __launch_bounds__(256,4) pins VGPR<=128 -> 16 waves/CU (50% occ, was 28%).
//  * Phase-2: all 8 x-loads of an ns-step hoisted (4 rows x 2 float4) -> 8-deep MLP
//    instead of 2 serial loads per dt.
// Dataflow unchanged vs v7: alpha never touches HBM; vlad via atomicAdd.
// B=32, D=512, K=64, N=3136.

#define NN 3136
#define DD 512
#define KK 64
#define BB 32

typedef short bf16x8 __attribute__((ext_vector_type(8)));
typedef float f32x4  __attribute__((ext_vector_type(4)));

#define SEL_HI   0x05040100u   // (a_low16<<16) | b_low16
#define SEL_LO   0x07060302u   // (a_high16<<16) | b_high16
#define SEL_PACK 0x07060302u   // a=lo_f32, b=x_f32 -> (lo_hi16<<16) | x_hi16

union FragU { uint4 u; bf16x8 f; };

static __device__ inline bf16x8 frag4(unsigned a, unsigned b, unsigned c, unsigned d) {
    FragU x; x.u = make_uint4(a, b, c, d); return x.f;
}

static __device__ inline unsigned short bf16_rne(float f) {
    unsigned u = __float_as_uint(f);
    return (unsigned short)((u + 0x7FFFu + ((u >> 16) & 1u)) >> 16);
}

// ---------------------------------------------------------------- wprep
// grid 1024: W split (i<32768), zero vlad (1M floats), zero asum.
__global__ __launch_bounds__(256) void wprep_kernel(
    const float* __restrict__ w, unsigned short* __restrict__ wh,
    unsigned short* __restrict__ wl, float* __restrict__ asum,
    float* __restrict__ vlad)
{
    const int i = blockIdx.x * 256 + threadIdx.x;    // < 262144
    if (i < 32768) {
        float v = w[i];
        float hif = __uint_as_float(__float_as_uint(v) & 0xFFFF0000u);
        float lof = v - hif;
        wh[i] = (unsigned short)(__float_as_uint(v) >> 16);
        wl[i] = (unsigned short)(__float_as_uint(lof) >> 16);
    }
    *(float4*)&vlad[(size_t)i * 4] = make_float4(0.f, 0.f, 0.f, 0.f);
    if (i < 2048) asum[i] = 0.f;
}

// ---------------------------------------------------------------- fused G1+G2
// grid (25, 32), block 256 (4 waves).
// Phase 1: logits+softmax+asum for 128 pixels, alpha -> LDS (bf16, [k][n]).
// Phase 2: vlad[d,k] partial GEMM over this block's 128 pixels, atomics out.
__global__ __launch_bounds__(256, 4) void fused_vlad(
    const float* __restrict__ x,          // [B,D,N] fp32
    const unsigned short* __restrict__ wh,// [64][512] hi
    const unsigned short* __restrict__ wl,// [64][512] lo
    const float* __restrict__ bias,       // [64]
    float* __restrict__ asum,             // [B,K] fp32 (pre-zeroed)
    float* __restrict__ vlad)             // [B,D,K] fp32 (pre-zeroed)
{
    const int b  = blockIdx.y;
    const int n0 = blockIdx.x * 128;
    const int t  = threadIdx.x;
    const int lane = t & 63;
    const int wv   = t >> 6;
    const int c = lane & 15;
    const int q = lane >> 4;

    // xs (phase 1, [128][36] u32 = 18432 B) and as_ (phase 2, [64][136] bf16
    // = 17408 B) have DISJOINT lifetimes -> share one region.
    __shared__ __align__(16) unsigned xs_raw[128 * 36];
    __shared__ __align__(16) unsigned short wsh[64][40];  // [k][d] hi
    __shared__ __align__(16) unsigned short wsl[64][40];  // [k][d] lo
    unsigned short* as_ = (unsigned short*)xs_raw;        // [64][136]

    f32x4 acc[4][2];
    #pragma unroll
    for (int mt = 0; mt < 4; mt++)
        #pragma unroll
        for (int r = 0; r < 4; r++) {
            float bv = bias[mt * 16 + q * 4 + r];
            acc[mt][0][r] = bv; acc[mt][1][r] = bv;
        }

    const float* xb = x + (size_t)b * DD * NN;
    const int n4 = t & 31;        // n offset within 32
    const int dr = t >> 5;        // 0..7 -> d col-group
    const int wrow = t >> 2, wc8 = t & 3;

    // ---- prefetch dc=0
    float xr[16];
    uint4 wrh, wrl;
    {
        #pragma unroll
        for (int j = 0; j < 4; j++) {
            int nn = n0 + n4 + 32 * j;
            if (nn > NN - 1) nn = NN - 1;
            #pragma unroll
            for (int p = 0; p < 4; p++)
                xr[j * 4 + p] = xb[(size_t)(dr * 4 + p) * NN + nn];
        }
        wrh = *(const uint4*)&wh[(size_t)wrow * DD + wc8 * 8];
        wrl = *(const uint4*)&wl[(size_t)wrow * DD + wc8 * 8];
    }

    for (int dc = 0; dc < 16; dc++) {
        // pack current regs (frees xr for the next prefetch)
        uint4 xp[4];
        #pragma unroll
        for (int j = 0; j < 4; j++) {
            unsigned pk[4];
            #pragma unroll
            for (int p = 0; p < 4; p++) {
                float v = xr[j * 4 + p];
                float hif = __uint_as_float(__float_as_uint(v) & 0xFFFF0000u);
                float lof = v - hif;
                pk[p] = __builtin_amdgcn_perm(__float_as_uint(lof), __float_as_uint(v), SEL_PACK);
            }
            xp[j] = make_uint4(pk[0], pk[1], pk[2], pk[3]);
        }
        uint4 wch = wrh, wcl = wrl;

        // prefetch dc+1 (in flight across the MFMA section below)
        if (dc < 15) {
            const int d0 = (dc + 1) * 32;
            #pragma unroll
            for (int j = 0; j < 4; j++) {
                int nn = n0 + n4 + 32 * j;
                if (nn > NN - 1) nn = NN - 1;
                #pragma unroll
                for (int p = 0; p < 4; p++)
                    xr[j * 4 + p] = xb[(size_t)(d0 + dr * 4 + p) * NN + nn];
            }
            wrh = *(const uint4*)&wh[(size_t)wrow * DD + d0 + wc8 * 8];
            wrl = *(const uint4*)&wl[(size_t)wrow * DD + d0 + wc8 * 8];
        }

        __syncthreads();   // prev LDS consumers done
        #pragma unroll
        for (int j = 0; j < 4; j++)
            *(uint4*)&xs_raw[(n4 + 32 * j) * 36 + dr * 4] = xp[j];
        *(uint4*)&wsh[wrow][wc8 * 8] = wch;
        *(uint4*)&wsl[wrow][wc8 * 8] = wcl;
        __syncthreads();   // LDS visible

        // fragments: A direct b128 from planes; B via perm from packed xs
        bf16x8 ah[4], al[4], bh[2], bl[2];
        #pragma unroll
        for (int mt = 0; mt < 4; mt++) {
            ah[mt] = *(const bf16x8*)&wsh[mt * 16 + c][q * 8];
            al[mt] = *(const bf16x8*)&wsl[mt * 16 + c][q * 8];
        }
        #pragma unroll
        for (int nt = 0; nt < 2; nt++) {
            const int row = wv * 32 + nt * 16 + c;
            uint4 p0 = *(const uint4*)&xs_raw[row * 36 + q * 8];
            uint4 p1 = *(const uint4*)&xs_raw[row * 36 + q * 8 + 4];
            bh[nt] = frag4(__builtin_amdgcn_perm(p0.y, p0.x, SEL_HI),
                           __builtin_amdgcn_perm(p0.w, p0.z, SEL_HI),
                           __builtin_amdgcn_perm(p1.y, p1.x, SEL_HI),
                           __builtin_amdgcn_perm(p1.w, p1.z, SEL_HI));
            bl[nt] = frag4(__builtin_amdgcn_perm(p0.y, p0.x, SEL_LO),
                           __builtin_amdgcn_perm(p0.w, p0.z, SEL_LO),
                           __builtin_amdgcn_perm(p1.y, p1.x, SEL_LO),
                           __builtin_amdgcn_perm(p1.w, p1.z, SEL_LO));
        }
        #pragma unroll
        for (int mt = 0; mt < 4; mt++)
            #pragma unroll
            for (int nt = 0; nt < 2; nt++) {
                acc[mt][nt] = __builtin_amdgcn_mfma_f32_16x16x32_bf16(ah[mt], bh[nt], acc[mt][nt], 0, 0, 0);
                acc[mt][nt] = __builtin_amdgcn_mfma_f32_16x16x32_bf16(ah[mt], bl[nt], acc[mt][nt], 0, 0, 0);
                acc[mt][nt] = __builtin_amdgcn_mfma_f32_16x16x32_bf16(al[mt], bh[nt], acc[mt][nt], 0, 0, 0);
            }
    }

    __syncthreads();   // xs lifetime ends here; as_ aliases it below

    // fused softmax over 64 clusters + bf16 -> LDS alpha + asum partials
    float sa[4][4];
    #pragma unroll
    for (int mt = 0; mt < 4; mt++)
        #pragma unroll
        for (int r = 0; r < 4; r++) sa[mt][r] = 0.f;

    #pragma unroll
    for (int nt = 0; nt < 2; nt++) {
        float mx = -1e30f;
        #pragma unroll
        for (int mt = 0; mt < 4; mt++)
            #pragma unroll
            for (int r = 0; r < 4; r++) mx = fmaxf(mx, acc[mt][nt][r]);
        mx = fmaxf(mx, __shfl_xor(mx, 16));
        mx = fmaxf(mx, __shfl_xor(mx, 32));
        float s = 0.f;
        #pragma unroll
        for (int mt = 0; mt < 4; mt++)
            #pragma unroll
            for (int r = 0; r < 4; r++) {
                float e = __expf(acc[mt][nt][r] - mx);
                acc[mt][nt][r] = e; s += e;
            }
        s += __shfl_xor(s, 16);
        s += __shfl_xor(s, 32);
        const float rinv = 1.0f / s;
        const int nloc = wv * 32 + nt * 16 + c;      // 0..127
        const bool ok = (n0 + nloc) < NN;
        #pragma unroll
        for (int mt = 0; mt < 4; mt++)
            #pragma unroll
            for (int r = 0; r < 4; r++) {
                unsigned short ub = bf16_rne(acc[mt][nt][r] * rinv);
                if (!ok) ub = 0;                      // invalid pixels contribute 0
                as_[(mt * 16 + q * 4 + r) * 136 + nloc] = ub;
                if (ok) sa[mt][r] += __uint_as_float((unsigned)ub << 16);  // dequantized
            }
    }
    #pragma unroll
    for (int off = 1; off <= 8; off <<= 1)
        #pragma unroll
        for (int mt = 0; mt < 4; mt++)
            #pragma unroll
            for (int r = 0; r < 4; r++)
                sa[mt][r] += __shfl_xor(sa[mt][r], off);
    if (c == 0) {
        #pragma unroll
        for (int mt = 0; mt < 4; mt++)
            #pragma unroll
            for (int r = 0; r < 4; r++)
                atomicAdd(&asum[b * KK + mt * 16 + q * 4 + r], sa[mt][r]);
    }

    __syncthreads();   // as_ visible to all waves

    // -------- phase 2: vlad[d,k] += sum_n x[d,n] * alpha[k,n] over 128 pixels
    // Wave wv owns d-rows [wv*128, wv*128+128). Two d-halves cap acc at 64 VGPR.
    // A-frag: x rows direct from global (L3-hot), hi/lo split; all 8 loads of an
    // ns-step issued before the pack/MFMA section (8-deep MLP).
    // B-frag: as_[k][n] ds_read_b128.
    const float* xw = x + ((size_t)b * DD + wv * 128) * NN;
    float* pvb = vlad + ((size_t)b * DD + wv * 128) * KK;

    #pragma unroll
    for (int dh = 0; dh < 2; dh++) {
        f32x4 acc2[4][4];
        #pragma unroll
        for (int dt = 0; dt < 4; dt++)
            #pragma unroll
            for (int kt = 0; kt < 4; kt++)
                #pragma unroll
                for (int r = 0; r < 4; r++) acc2[dt][kt][r] = 0.f;

        #pragma unroll
        for (int ns = 0; ns < 4; ns++) {
            int nn = n0 + ns * 32 + q * 8;           // multiple of 8
            if (nn > NN - 8) nn = NN - 8;            // clamp: alpha=0 there anyway
            // batched x loads: 4 rows x 2 float4, all in flight together
            float4 xv[4][2];
            #pragma unroll
            for (int dt = 0; dt < 4; dt++) {
                const size_t ro = (size_t)(dh * 64 + dt * 16 + c) * NN;
                xv[dt][0] = *(const float4*)&xw[ro + nn];
                xv[dt][1] = *(const float4*)&xw[ro + nn + 4];
            }
            bf16x8 bfr[4];
            #pragma unroll
            for (int kt = 0; kt < 4; kt++)
                bfr[kt] = *(const bf16x8*)&as_[(kt * 16 + c) * 136 + ns * 32 + q * 8];
            #pragma unroll
            for (int dt = 0; dt < 4; dt++) {
                const float4 va = xv[dt][0], vb2 = xv[dt][1];
                unsigned ux = __float_as_uint(va.x),  uy = __float_as_uint(va.y);
                unsigned uz = __float_as_uint(va.z),  uw = __float_as_uint(va.w);
                unsigned vx = __float_as_uint(vb2.x), vy = __float_as_uint(vb2.y);
                unsigned vz = __float_as_uint(vb2.z), vw = __float_as_uint(vb2.w);
                bf16x8 ah = frag4(__builtin_amdgcn_perm(uy, ux, SEL_LO),
                                  __builtin_amdgcn_perm(uw, uz, SEL_LO),
                                  __builtin_amdgcn_perm(vy, vx, SEL_LO),
                                  __builtin_amdgcn_perm(vw, vz, SEL_LO));
                float lax = va.x - __uint_as_float(ux & 0xFFFF0000u);
                float lay = va.y - __uint_as_float(uy & 0xFFFF0000u);
                float laz = va.z - __uint_as_float(uz & 0xFFFF0000u);
                float law = va.w - __uint_as_float(uw & 0xFFFF0000u);
                float lbx = vb2.x - __uint_as_float(vx & 0xFFFF0000u);
                float lby = vb2.y - __uint_as_float(vy & 0xFFFF0000u);
                float lbz = vb2.z - __uint_as_float(vz & 0xFFFF0000u);
                float lbw = vb2.w - __uint_as_float(vw & 0xFFFF0000u);
                bf16x8 al2 = frag4(
                    __builtin_amdgcn_perm(__float_as_uint(lay), __float_as_uint(lax), SEL_LO),
                    __builtin_amdgcn_perm(__float_as_uint(law), __float_as_uint(laz), SEL_LO),
                    __builtin_amdgcn_perm(__float_as_uint(lby), __float_as_uint(lbx), SEL_LO),
                    __builtin_amdgcn_perm(__float_as_uint(lbw), __float_as_uint(lbz), SEL_LO));
                #pragma unroll
                for (int kt = 0; kt < 4; kt++) {
                    acc2[dt][kt] = __builtin_amdgcn_mfma_f32_16x16x32_bf16(ah,  bfr[kt], acc2[dt][kt], 0, 0, 0);
                    acc2[dt][kt] = __builtin_amdgcn_mfma_f32_16x16x32_bf16(al2, bfr[kt], acc2[dt][kt], 0, 0, 0);
                }
            }
        }
        #pragma unroll
        for (int dt = 0; dt < 4; dt++)
            #pragma unroll
            for (int r = 0; r < 4; r++) {
                const size_t dl = (size_t)(dh * 64 + dt * 16 + q * 4 + r) * KK;
                #pragma unroll
                for (int kt = 0; kt < 4; kt++)
                    atomicAdd(&pvb[dl + kt * 16 + c], acc2[dt][kt][r]);
            }
    }
}

// ---------------------------------------------------------------- combine
// grid (4, 32): vlad -= centers*asum (in place), psq partial sq-sums.
__global__ __launch_bounds__(256) void combine_norm(
    const float* __restrict__ centers, const float* __restrict__ asum,
    float* __restrict__ vlad, float* __restrict__ psq)
{
    const int dchunk = blockIdx.x;
    const int b = blockIdx.y;
    const int t = threadIdx.x;
    const int k4 = (t & 15) * 4;
    const int dq = t >> 4;          // 0..15
    const float4 av = *(const float4*)&asum[b * KK + k4];
    float sqx = 0.f, sqy = 0.f, sqz = 0.f, sqw = 0.f;
    for (int i = 0; i < 8; i++) {
        const int d = dchunk * 128 + i * 16 + dq;
        const size_t idx = ((size_t)b * DD + d) * KK + k4;
        float4 p = *(const float4*)&vlad[idx];
        const float4 cv = *(const float4*)&centers[d * KK + k4];
        float vx = p.x - cv.x * av.x, vy = p.y - cv.y * av.y;
        float vz = p.z - cv.z * av.z, vw = p.w - cv.w * av.w;
        *(float4*)&vlad[idx] = make_float4(vx, vy, vz, vw);
        sqx = fmaf(vx, vx, sqx); sqy = fmaf(vy, vy, sqy);
        sqz = fmaf(vz, vz, sqz); sqw = fmaf(vw, vw, sqw);
    }
    __shared__ float red[16][64];
    red[dq][k4 + 0] = sqx; red[dq][k4 + 1] = sqy;
    red[dq][k4 + 2] = sqz; red[dq][k4 + 3] = sqw;
    __syncthreads();
    if (t < 64) {
        float s = 0.f;
        #pragma unroll
        for (int qq = 0; qq < 16; qq++) s += red[qq][t];
        psq[(b * 4 + dchunk) * 64 + t] = s;
    }
}

// ---------------------------------------------------------------- finalize
__global__ __launch_bounds__(256) void finalize_kernel(
    const float* __restrict__ psq, const float* __restrict__ vlad,
    float* __restrict__ out)
{
    const int dchunk = blockIdx.x;
    const int b = blockIdx.y;
    const int t = threadIdx.x;
    __shared__ float cn[64];
    if (t < 64) {
        float s = psq[b * 256 + t] + psq[b * 256 + 64 + t]
                + psq[b * 256 + 128 + t] + psq[b * 256 + 192 + t];
        cn[t] = 1.0f / (sqrtf(s) * 8.0f);   // global norm of K unit cols == 8
    }
    __syncthreads();
    const int k4 = (t & 15) * 4;
    const int dq = t >> 4;
    const float4 cv = *(const float4*)&cn[k4];
    #pragma unroll
    for (int i = 0; i < 8; i++) {
        const size_t idx = ((size_t)b * DD + dchunk * 128 + i * 16 + dq) * KK + k4;
        float4 v = *(const float4*)&vlad[idx];
        *(float4*)&out[idx] = make_float4(v.x * cv.x, v.y * cv.y, v.z * cv.z, v.w * cv.w);
    }
}

// ---------------------------------------------------------------- launch
extern "C" void kernel_launch(void* const* d_in, const int* in_sizes, int n_in,
                              void* d_out, int out_size, void* d_ws, size_t ws_size,
                              hipStream_t stream) {
    const float* x       = (const float*)d_in[0];
    const float* conv_w  = (const float*)d_in[1];
    const float* conv_b  = (const float*)d_in[2];
    const float* centers = (const float*)d_in[3];
    float* out = (float*)d_out;

    unsigned short* wh = (unsigned short*)d_ws;     // 32768 ushort
    unsigned short* wl = wh + 32768;                // 32768 ushort
    float* asum = (float*)(wl + 32768);             // 2048
    float* vlad = asum + 2048;                      // 1,048,576
    float* psq  = vlad + 1048576;                   // 8192

    wprep_kernel   <<<dim3(1024),    dim3(256), 0, stream>>>(conv_w, wh, wl, asum, vlad);
    fused_vlad     <<<dim3(25, BB),  dim3(256), 0, stream>>>(x, wh, wl, conv_b, asum, vlad);
    combine_norm   <<<dim3(4, BB),   dim3(256), 0, stream>>>(centers, asum, vlad, psq);
    finalize_kernel<<<dim3(4, BB),   dim3(256), 0, stream>>>(psq, vlad, out);
}

// Round 4
// 406.856 us; speedup vs baseline: 1.0200x; 1.0031x over previous
//
#include <hip/hip_runtime.h>
#include <math.h>

// NetVLAD v9 — fused G1+G2, phase-2 rebuilt:
//  * alpha B-fragments hoisted to registers (bfr[4], 16 VGPR) right after
//    softmax -> as_ LDS dies, region reused for x staging.
//  * phase 2: 16 chunks x 32 d-rows, x staged coalesced (float4, reg-prefetched
//    one chunk ahead; ch=0 loads issued before softmax) -> packed hi|lo u32 in
//    xs2[32][132] (stride 132 u32 == 4 mod 32 banks -> conflict-free quarters)
//    -> ds_read_b128 + perm fragments. No scattered global 16B loads.
//  * atomic flush spread per chunk (8/thread/chunk) instead of 128-deep burst.
// LDS 28672 B total (xs2 overlays dead phase-1 region). B=32, D=512, K=64, N=3136.

#define NN 3136
#define DD 512
#define KK 64
#define BB 32

typedef short bf16x8 __attribute__((ext_vector_type(8)));
typedef float f32x4  __attribute__((ext_vector_type(4)));

#define SEL_HI   0x05040100u   // (a_low16<<16) | b_low16
#define SEL_LO   0x07060302u   // (a_high16<<16) | b_high16
#define SEL_PACK 0x07060302u   // a=lo_f32, b=x_f32 -> (lo_hi16<<16) | x_hi16

union FragU { uint4 u; bf16x8 f; };

static __device__ inline bf16x8 frag4(unsigned a, unsigned b, unsigned c, unsigned d) {
    FragU x; x.u = make_uint4(a, b, c, d); return x.f;
}

static __device__ inline unsigned short bf16_rne(float f) {
    unsigned u = __float_as_uint(f);
    return (unsigned short)((u + 0x7FFFu + ((u >> 16) & 1u)) >> 16);
}

// ---------------------------------------------------------------- wprep
__global__ __launch_bounds__(256) void wprep_kernel(
    const float* __restrict__ w, unsigned short* __restrict__ wh,
    unsigned short* __restrict__ wl, float* __restrict__ asum,
    float* __restrict__ vlad)
{
    const int i = blockIdx.x * 256 + threadIdx.x;    // < 262144
    if (i < 32768) {
        float v = w[i];
        float hif = __uint_as_float(__float_as_uint(v) & 0xFFFF0000u);
        float lof = v - hif;
        wh[i] = (unsigned short)(__float_as_uint(v) >> 16);
        wl[i] = (unsigned short)(__float_as_uint(lof) >> 16);
    }
    *(float4*)&vlad[(size_t)i * 4] = make_float4(0.f, 0.f, 0.f, 0.f);
    if (i < 2048) asum[i] = 0.f;
}

// ---------------------------------------------------------------- fused G1+G2
// grid (25, 32), block 256 (4 waves).
__global__ __launch_bounds__(256, 4) void fused_vlad(
    const float* __restrict__ x,          // [B,D,N] fp32
    const unsigned short* __restrict__ wh,// [64][512] hi
    const unsigned short* __restrict__ wl,// [64][512] lo
    const float* __restrict__ bias,       // [64]
    float* __restrict__ asum,             // [B,K] fp32 (pre-zeroed)
    float* __restrict__ vlad)             // [B,D,K] fp32 (pre-zeroed)
{
    const int b  = blockIdx.y;
    const int n0 = blockIdx.x * 128;
    const int t  = threadIdx.x;
    const int lane = t & 63;
    const int wv   = t >> 6;
    const int c = lane & 15;
    const int q = lane >> 4;

    // One 28672-B region, carved per phase:
    //  phase 1: xs[128][36] u32 (18432) | wsh[64][40] u16 (5120) | wsl[64][40] (5120)
    //  softmax: as_[64][136] u16 (17408) at offset 0 (aliases dead xs)
    //  phase 2: xs2[32][132] u32 (16896) at offset 0 (aliases dead as_, after bfr hoist)
    __shared__ __align__(16) unsigned char smem[28672];
    unsigned*       xs_raw = (unsigned*)smem;
    unsigned short* wsh    = (unsigned short*)(smem + 18432);
    unsigned short* wsl    = (unsigned short*)(smem + 23552);
    unsigned short* as_    = (unsigned short*)smem;
    unsigned*       xs2    = (unsigned*)smem;

    f32x4 acc[4][2];
    #pragma unroll
    for (int mt = 0; mt < 4; mt++)
        #pragma unroll
        for (int r = 0; r < 4; r++) {
            float bv = bias[mt * 16 + q * 4 + r];
            acc[mt][0][r] = bv; acc[mt][1][r] = bv;
        }

    const float* xb = x + (size_t)b * DD * NN;
    const int n4 = t & 31;        // n offset within 32
    const int dr = t >> 5;        // 0..7 -> d col-group
    const int wrow = t >> 2, wc8 = t & 3;

    // ---- prefetch dc=0
    float xr[16];
    uint4 wrh, wrl;
    {
        #pragma unroll
        for (int j = 0; j < 4; j++) {
            int nn = n0 + n4 + 32 * j;
            if (nn > NN - 1) nn = NN - 1;
            #pragma unroll
            for (int p = 0; p < 4; p++)
                xr[j * 4 + p] = xb[(size_t)(dr * 4 + p) * NN + nn];
        }
        wrh = *(const uint4*)&wh[(size_t)wrow * DD + wc8 * 8];
        wrl = *(const uint4*)&wl[(size_t)wrow * DD + wc8 * 8];
    }

    for (int dc = 0; dc < 16; dc++) {
        uint4 xp[4];
        #pragma unroll
        for (int j = 0; j < 4; j++) {
            unsigned pk[4];
            #pragma unroll
            for (int p = 0; p < 4; p++) {
                float v = xr[j * 4 + p];
                float hif = __uint_as_float(__float_as_uint(v) & 0xFFFF0000u);
                float lof = v - hif;
                pk[p] = __builtin_amdgcn_perm(__float_as_uint(lof), __float_as_uint(v), SEL_PACK);
            }
            xp[j] = make_uint4(pk[0], pk[1], pk[2], pk[3]);
        }
        uint4 wch = wrh, wcl = wrl;

        if (dc < 15) {
            const int d0 = (dc + 1) * 32;
            #pragma unroll
            for (int j = 0; j < 4; j++) {
                int nn = n0 + n4 + 32 * j;
                if (nn > NN - 1) nn = NN - 1;
                #pragma unroll
                for (int p = 0; p < 4; p++)
                    xr[j * 4 + p] = xb[(size_t)(d0 + dr * 4 + p) * NN + nn];
            }
            wrh = *(const uint4*)&wh[(size_t)wrow * DD + d0 + wc8 * 8];
            wrl = *(const uint4*)&wl[(size_t)wrow * DD + d0 + wc8 * 8];
        }

        __syncthreads();   // prev LDS consumers done
        #pragma unroll
        for (int j = 0; j < 4; j++)
            *(uint4*)&xs_raw[(n4 + 32 * j) * 36 + dr * 4] = xp[j];
        *(uint4*)&wsh[wrow * 40 + wc8 * 8] = wch;
        *(uint4*)&wsl[wrow * 40 + wc8 * 8] = wcl;
        __syncthreads();   // LDS visible

        bf16x8 ah[4], al[4], bh[2], bl[2];
        #pragma unroll
        for (int mt = 0; mt < 4; mt++) {
            ah[mt] = *(const bf16x8*)&wsh[(mt * 16 + c) * 40 + q * 8];
            al[mt] = *(const bf16x8*)&wsl[(mt * 16 + c) * 40 + q * 8];
        }
        #pragma unroll
        for (int nt = 0; nt < 2; nt++) {
            const int row = wv * 32 + nt * 16 + c;
            uint4 p0 = *(const uint4*)&xs_raw[row * 36 + q * 8];
            uint4 p1 = *(const uint4*)&xs_raw[row * 36 + q * 8 + 4];
            bh[nt] = frag4(__builtin_amdgcn_perm(p0.y, p0.x, SEL_HI),
                           __builtin_amdgcn_perm(p0.w, p0.z, SEL_HI),
                           __builtin_amdgcn_perm(p1.y, p1.x, SEL_HI),
                           __builtin_amdgcn_perm(p1.w, p1.z, SEL_HI));
            bl[nt] = frag4(__builtin_amdgcn_perm(p0.y, p0.x, SEL_LO),
                           __builtin_amdgcn_perm(p0.w, p0.z, SEL_LO),
                           __builtin_amdgcn_perm(p1.y, p1.x, SEL_LO),
                           __builtin_amdgcn_perm(p1.w, p1.z, SEL_LO));
        }
        #pragma unroll
        for (int mt = 0; mt < 4; mt++)
            #pragma unroll
            for (int nt = 0; nt < 2; nt++) {
                acc[mt][nt] = __builtin_amdgcn_mfma_f32_16x16x32_bf16(ah[mt], bh[nt], acc[mt][nt], 0, 0, 0);
                acc[mt][nt] = __builtin_amdgcn_mfma_f32_16x16x32_bf16(ah[mt], bl[nt], acc[mt][nt], 0, 0, 0);
                acc[mt][nt] = __builtin_amdgcn_mfma_f32_16x16x32_bf16(al[mt], bh[nt], acc[mt][nt], 0, 0, 0);
            }
    }

    __syncthreads();   // phase-1 LDS dead; as_ aliasing begins

    // ---- prefetch phase-2 chunk 0 (flies during softmax)
    const int sr = t >> 4;          // 0..15: staging row within 16-row half
    const int sc = (t & 15) * 8;    // 0..120: n-col group
    int ncol = n0 + sc; if (ncol > NN - 8) ncol = NN - 8;
    float4 sxr[2][2];
    #pragma unroll
    for (int i = 0; i < 2; i++) {
        const size_t ro = (size_t)(i * 16 + sr) * NN;   // ch=0 -> d-rows 0..31
        sxr[i][0] = *(const float4*)&xb[ro + ncol];
        sxr[i][1] = *(const float4*)&xb[ro + ncol + 4];
    }

    // fused softmax over 64 clusters + bf16 -> LDS alpha + asum partials
    float sa[4][4];
    #pragma unroll
    for (int mt = 0; mt < 4; mt++)
        #pragma unroll
        for (int r = 0; r < 4; r++) sa[mt][r] = 0.f;

    #pragma unroll
    for (int nt = 0; nt < 2; nt++) {
        float mx = -1e30f;
        #pragma unroll
        for (int mt = 0; mt < 4; mt++)
            #pragma unroll
            for (int r = 0; r < 4; r++) mx = fmaxf(mx, acc[mt][nt][r]);
        mx = fmaxf(mx, __shfl_xor(mx, 16));
        mx = fmaxf(mx, __shfl_xor(mx, 32));
        float s = 0.f;
        #pragma unroll
        for (int mt = 0; mt < 4; mt++)
            #pragma unroll
            for (int r = 0; r < 4; r++) {
                float e = __expf(acc[mt][nt][r] - mx);
                acc[mt][nt][r] = e; s += e;
            }
        s += __shfl_xor(s, 16);
        s += __shfl_xor(s, 32);
        const float rinv = 1.0f / s;
        const int nloc = wv * 32 + nt * 16 + c;      // 0..127
        const bool ok = (n0 + nloc) < NN;
        #pragma unroll
        for (int mt = 0; mt < 4; mt++)
            #pragma unroll
            for (int r = 0; r < 4; r++) {
                unsigned short ub = bf16_rne(acc[mt][nt][r] * rinv);
                if (!ok) ub = 0;                      // invalid pixels contribute 0
                as_[(mt * 16 + q * 4 + r) * 136 + nloc] = ub;
                if (ok) sa[mt][r] += __uint_as_float((unsigned)ub << 16);  // dequantized
            }
    }
    #pragma unroll
    for (int off = 1; off <= 8; off <<= 1)
        #pragma unroll
        for (int mt = 0; mt < 4; mt++)
            #pragma unroll
            for (int r = 0; r < 4; r++)
                sa[mt][r] += __shfl_xor(sa[mt][r], off);
    if (c == 0) {
        #pragma unroll
        for (int mt = 0; mt < 4; mt++)
            #pragma unroll
            for (int r = 0; r < 4; r++)
                atomicAdd(&asum[b * KK + mt * 16 + q * 4 + r], sa[mt][r]);
    }

    __syncthreads();   // as_ visible

    // ---- hoist alpha B-fragments to registers: wave owns k-cols wv*16..+16.
    // bfr[ns]: lane (c,q) holds alpha[k=wv*16+c][n = ns*32+q*8 .. +8].
    bf16x8 bfr[4];
    #pragma unroll
    for (int ns = 0; ns < 4; ns++)
        bfr[ns] = *(const bf16x8*)&as_[(wv * 16 + c) * 136 + ns * 32 + q * 8];
    // as_ is DEAD after the next barrier; xs2 overlays it.

    // -------- phase 2: vlad[d, wv*16..+16] += sum_n x[d,n]*alpha[k,n]
    // 16 chunks x 32 d-rows; x staged coalesced + packed hi|lo into xs2[32][132].
    float* pvb = vlad + (size_t)b * DD * KK + wv * 16;

    for (int ch = 0; ch < 16; ch++) {
        // pack current staged regs (2 x 8 f32 -> 2 x 8 packed u32)
        unsigned pk[2][8];
        #pragma unroll
        for (int i = 0; i < 2; i++) {
            const float vv[8] = { sxr[i][0].x, sxr[i][0].y, sxr[i][0].z, sxr[i][0].w,
                                  sxr[i][1].x, sxr[i][1].y, sxr[i][1].z, sxr[i][1].w };
            #pragma unroll
            for (int j = 0; j < 8; j++) {
                unsigned u = __float_as_uint(vv[j]);
                float lo = vv[j] - __uint_as_float(u & 0xFFFF0000u);
                pk[i][j] = __builtin_amdgcn_perm(__float_as_uint(lo), u, SEL_PACK);
            }
        }
        // prefetch next chunk
        if (ch < 15) {
            const size_t dbase = (size_t)(ch + 1) * 32;
            #pragma unroll
            for (int i = 0; i < 2; i++) {
                const size_t ro = (dbase + i * 16 + sr) * NN;
                sxr[i][0] = *(const float4*)&xb[ro + ncol];
                sxr[i][1] = *(const float4*)&xb[ro + ncol + 4];
            }
        }

        __syncthreads();   // (ch=0: bfr hoist done) / prev chunk reads done
        #pragma unroll
        for (int i = 0; i < 2; i++) {
            *(uint4*)&xs2[(i * 16 + sr) * 132 + sc]     = make_uint4(pk[i][0], pk[i][1], pk[i][2], pk[i][3]);
            *(uint4*)&xs2[(i * 16 + sr) * 132 + sc + 4] = make_uint4(pk[i][4], pk[i][5], pk[i][6], pk[i][7]);
        }
        __syncthreads();   // staged tile visible

        f32x4 a2[2];
        #pragma unroll
        for (int dt = 0; dt < 2; dt++)
            #pragma unroll
            for (int r = 0; r < 4; r++) a2[dt][r] = 0.f;

        #pragma unroll
        for (int ns = 0; ns < 4; ns++) {
            #pragma unroll
            for (int dt = 0; dt < 2; dt++) {
                const int base = (dt * 16 + c) * 132 + ns * 32 + q * 8;
                uint4 p0 = *(const uint4*)&xs2[base];
                uint4 p1 = *(const uint4*)&xs2[base + 4];
                bf16x8 ah = frag4(__builtin_amdgcn_perm(p0.y, p0.x, SEL_HI),
                                  __builtin_amdgcn_perm(p0.w, p0.z, SEL_HI),
                                  __builtin_amdgcn_perm(p1.y, p1.x, SEL_HI),
                                  __builtin_amdgcn_perm(p1.w, p1.z, SEL_HI));
                bf16x8 al2 = frag4(__builtin_amdgcn_perm(p0.y, p0.x, SEL_LO),
                                   __builtin_amdgcn_perm(p0.w, p0.z, SEL_LO),
                                   __builtin_amdgcn_perm(p1.y, p1.x, SEL_LO),
                                   __builtin_amdgcn_perm(p1.w, p1.z, SEL_LO));
                a2[dt] = __builtin_amdgcn_mfma_f32_16x16x32_bf16(ah,  bfr[ns], a2[dt], 0, 0, 0);
                a2[dt] = __builtin_amdgcn_mfma_f32_16x16x32_bf16(al2, bfr[ns], a2[dt], 0, 0, 0);
            }
        }

        // flush this chunk (fire-and-forget atomics overlap next chunk)
        #pragma unroll
        for (int dt = 0; dt < 2; dt++)
            #pragma unroll
            for (int r = 0; r < 4; r++) {
                const int d = ch * 32 + dt * 16 + q * 4 + r;
                atomicAdd(&pvb[(size_t)d * KK + c], a2[dt][r]);
            }
    }
}

// ---------------------------------------------------------------- combine
__global__ __launch_bounds__(256) void combine_norm(
    const float* __restrict__ centers, const float* __restrict__ asum,
    float* __restrict__ vlad, float* __restrict__ psq)
{
    const int dchunk = blockIdx.x;
    const int b = blockIdx.y;
    const int t = threadIdx.x;
    const int k4 = (t & 15) * 4;
    const int dq = t >> 4;          // 0..15
    const float4 av = *(const float4*)&asum[b * KK + k4];
    float sqx = 0.f, sqy = 0.f, sqz = 0.f, sqw = 0.f;
    for (int i = 0; i < 8; i++) {
        const int d = dchunk * 128 + i * 16 + dq;
        const size_t idx = ((size_t)b * DD + d) * KK + k4;
        float4 p = *(const float4*)&vlad[idx];
        const float4 cv = *(const float4*)&centers[d * KK + k4];
        float vx = p.x - cv.x * av.x, vy = p.y - cv.y * av.y;
        float vz = p.z - cv.z * av.z, vw = p.w - cv.w * av.w;
        *(float4*)&vlad[idx] = make_float4(vx, vy, vz, vw);
        sqx = fmaf(vx, vx, sqx); sqy = fmaf(vy, vy, sqy);
        sqz = fmaf(vz, vz, sqz); sqw = fmaf(vw, vw, sqw);
    }
    __shared__ float red[16][64];
    red[dq][k4 + 0] = sqx; red[dq][k4 + 1] = sqy;
    red[dq][k4 + 2] = sqz; red[dq][k4 + 3] = sqw;
    __syncthreads();
    if (t < 64) {
        float s = 0.f;
        #pragma unroll
        for (int qq = 0; qq < 16; qq++) s += red[qq][t];
        psq[(b * 4 + dchunk) * 64 + t] = s;
    }
}

// ---------------------------------------------------------------- finalize
__global__ __launch_bounds__(256) void finalize_kernel(
    const float* __restrict__ psq, const float* __restrict__ vlad,
    float* __restrict__ out)
{
    const int dchunk = blockIdx.x;
    const int b = blockIdx.y;
    const int t = threadIdx.x;
    __shared__ float cn[64];
    if (t < 64) {
        float s = psq[b * 256 + t] + psq[b * 256 + 64 + t]
                + psq[b * 256 + 128 + t] + psq[b * 256 + 192 + t];
        cn[t] = 1.0f / (sqrtf(s) * 8.0f);   // global norm of K unit cols == 8
    }
    __syncthreads();
    const int k4 = (t & 15) * 4;
    const int dq = t >> 4;
    const float4 cv = *(const float4*)&cn[k4];
    #pragma unroll
    for (int i = 0; i < 8; i++) {
        const size_t idx = ((size_t)b * DD + dchunk * 128 + i * 16 + dq) * KK + k4;
        float4 v = *(const float4*)&vlad[idx];
        *(float4*)&out[idx] = make_float4(v.x * cv.x, v.y * cv.y, v.z * cv.z, v.w * cv.w);
    }
}

// ---------------------------------------------------------------- launch
extern "C" void kernel_launch(void* const* d_in, const int* in_sizes, int n_in,
                              void* d_out, int out_size, void* d_ws, size_t ws_size,
                              hipStream_t stream) {
    const float* x       = (const float*)d_in[0];
    const float* conv_w  = (const float*)d_in[1];
    const float* conv_b  = (const float*)d_in[2];
    const float* centers = (const float*)d_in[3];
    float* out = (float*)d_out;

    unsigned short* wh = (unsigned short*)d_ws;     // 32768 ushort
    unsigned short* wl = wh + 32768;                // 32768 ushort
    float* asum = (float*)(wl + 32768);             // 2048
    float* vlad = asum + 2048;                      // 1,048,576
    float* psq  = vlad + 1048576;                   // 8192

    wprep_kernel   <<<dim3(1024),    dim3(256), 0, stream>>>(conv_w, wh, wl, asum, vlad);
    fused_vlad     <<<dim3(25, BB),  dim3(256), 0, stream>>>(x, wh, wl, conv_b, asum, vlad);
    combine_norm   <<<dim3(4, BB),   dim3(256), 0, stream>>>(centers, asum, vlad, psq);
    finalize_kernel<<<dim3(4, BB),   dim3(256), 0, stream>>>(psq, vlad, out);
}